// Round 9
// baseline (459.995 us; speedup 1.0000x reference)
//
#include <hip/hip_runtime.h>

#define N_NODES 50000
#define N_EDGES 800000
#define NP 50048          // N padded
#define BKT 784           // nodes per bucket (64 buckets x 784 = 50176 >= N)
#define NBKT 64
#define HB 782            // hist/scatter blocks: 782*1024 >= 800000
#define PADK 136          // 128 + 8 bf16 pad
#define NCOPY 64          // BN-stat replication
#define WPB 512           // wprep blocks

typedef __bf16 bf16_8 __attribute__((ext_vector_type(8)));
typedef float  f32_4  __attribute__((ext_vector_type(4)));

__device__ inline float2 bf2f2(unsigned int u) {
    union { unsigned int i; float f; } a, b;
    a.i = u << 16;
    b.i = u & 0xffff0000u;
    return make_float2(a.f, b.f);
}

// ---------------- init (colpart/out_head) + weight transpose + svec ----------------
__global__ void k_init_wprep(float* __restrict__ colpart, float* __restrict__ out_head,
                             const float* __restrict__ conv_w, const float* __restrict__ lin1_w,
                             __bf16* __restrict__ WT, float* __restrict__ svec) {
    int b = blockIdx.x;
    if (b < 64) {
        int i = b * 256 + threadIdx.x;        // 64*256 = 16384 = 2*NCOPY*128
        colpart[i] = 0.f;
        if (i < 32) out_head[i] = 0.f;
    } else if (b < 64 + WPB) {
        int b2 = b - 64;                      // 0..511
        int mat = b2 >> 7, n = b2 & 127, k = threadIdx.x;
        if (k < 128) {
            const float* srcm = (mat < 3) ? (conv_w + (size_t)mat * 16384) : lin1_w;
            WT[((size_t)mat * 128 + n) * 128 + k] = (__bf16)srcm[(size_t)k * 128 + n];
        }
    } else {
        int j = threadIdx.x;                  // svec = colsum of lin1_w rows 256..511
        if (j < 128) {
            float s = 0.f;
            for (int k = 256; k < 512; ++k) s += lin1_w[(size_t)k * 128 + j];
            svec[j] = s;
        }
    }
}

// ---------------- CSR build pass 1: per-block bucket histogram (LDS atomics only) ----------------
__global__ void k_hist(const int* __restrict__ dst, int* __restrict__ counts) {
    __shared__ int c[NBKT];
    int t = threadIdx.x, b = blockIdx.x;
    if (t < NBKT) c[t] = 0;
    __syncthreads();
    int e0 = b * 1024;
    for (int i = t; i < 1024; i += 256) {
        int e = e0 + i;
        if (e < N_EDGES) atomicAdd(&c[dst[e] / BKT], 1);
    }
    __syncthreads();
    if (t < NBKT) counts[t * HB + b] = c[t];
}

// ---------------- CSR build pass 2: exclusive scan of counts[64][782] (one block) ----------------
__global__ void k_scan(int* __restrict__ counts, int* __restrict__ bucketStart) {
    __shared__ int p[256];
    int t = threadIdx.x;
    int base = t * 196;                        // 256*196 = 50176 >= 64*782 = 50048
    int sum = 0;
    for (int i = 0; i < 196; ++i) {
        int f = base + i;
        if (f < NBKT * HB) sum += counts[f];
    }
    p[t] = sum;
    __syncthreads();
    int own = sum;
    for (int d = 1; d < 256; d <<= 1) {
        int v = (t >= d) ? p[t - d] : 0;
        __syncthreads();
        p[t] += v;
        __syncthreads();
    }
    int run = p[t] - own;
    for (int i = 0; i < 196; ++i) {
        int f = base + i;
        if (f < NBKT * HB) {
            int v = counts[f];
            counts[f] = run;
            if (f % HB == 0) bucketStart[f / HB] = run;
            run += v;
        }
    }
}

// ---------------- CSR build pass 3: scatter to bucket-sorted ebuf (LDS atomics only) ------------
__global__ void k_scatter(const int* __restrict__ src, const int* __restrict__ dst,
                          const float* __restrict__ ew, const int* __restrict__ counts,
                          uint2* __restrict__ ebuf) {
    __shared__ int ofs[NBKT];
    int t = threadIdx.x, b = blockIdx.x;
    if (t < NBKT) ofs[t] = counts[t * HB + b];
    __syncthreads();
    int e0 = b * 1024;
    for (int i = t; i < 1024; i += 256) {
        int e = e0 + i;
        if (e < N_EDGES) {
            int d = dst[e];
            int bkt = d / BKT, dl = d - bkt * BKT;       // dl < 784 < 2^10
            int pos = atomicAdd(&ofs[bkt], 1);
            ebuf[pos] = make_uint2(((unsigned)dl << 17) | (unsigned)src[e],
                                   __float_as_uint(ew[e]));
        }
    }
}

// ---------------- CSR build pass 4: one block per bucket -> compact per-node CSR + dinv ---------
// Fuses weighted-degree/dinv (kills k_node) and pre-multiplies ew*dinv[dst].
__global__ __launch_bounds__(256) void k_build(const uint2* __restrict__ ebuf,
                                               const int* __restrict__ bucketStart,
                                               uint2* __restrict__ esn2,
                                               int* __restrict__ offs, int* __restrict__ cnt,
                                               float* __restrict__ dinv) {
    __shared__ int   c784[1024];
    __shared__ float deg784[1024];
    __shared__ int   o784[1024];
    __shared__ int   fill784[1024];
    __shared__ int   p[256];
    int b = blockIdx.x, t = threadIdx.x;
    int base = bucketStart[b];
    int end  = (b == NBKT - 1) ? N_EDGES : bucketStart[b + 1];
    for (int i = t; i < 1024; i += 256) { c784[i] = 0; deg784[i] = 1.0f; fill784[i] = 0; }
    __syncthreads();
    for (int i = base + t; i < end; i += 256) {
        uint2 eu = ebuf[i];
        int dl = eu.x >> 17;
        atomicAdd(&c784[dl], 1);
        atomicAdd(&deg784[dl], __uint_as_float(eu.y));   // LDS float atomic
    }
    __syncthreads();
    for (int i = t; i < BKT; i += 256) deg784[i] = rsqrtf(deg784[i]);   // now holds dinv
    // exclusive scan of c784 (4 elems/thread, padded to 1024)
    int s0 = c784[4 * t] + c784[4 * t + 1] + c784[4 * t + 2] + c784[4 * t + 3];
    p[t] = s0;
    __syncthreads();
    int own = s0;
    for (int d = 1; d < 256; d <<= 1) {
        int v = (t >= d) ? p[t - d] : 0;
        __syncthreads();
        p[t] += v;
        __syncthreads();
    }
    int e0 = p[t] - own;
    o784[4 * t] = e0;
    o784[4 * t + 1] = e0 + c784[4 * t];
    o784[4 * t + 2] = e0 + c784[4 * t] + c784[4 * t + 1];
    o784[4 * t + 3] = e0 + c784[4 * t] + c784[4 * t + 1] + c784[4 * t + 2];
    __syncthreads();
    int nb0 = b * BKT;
    for (int i = t; i < BKT; i += 256) {
        int n = nb0 + i;
        if (n < N_NODES) { offs[n] = base + o784[i]; cnt[n] = c784[i]; dinv[n] = deg784[i]; }
    }
    __syncthreads();
    for (int i = base + t; i < end; i += 256) {
        uint2 eu = ebuf[i];
        int dl = eu.x >> 17;
        int s  = (int)(eu.x & 131071u);
        int pos = base + o784[dl] + atomicAdd(&fill784[dl], 1);
        esn2[pos] = make_uint2((unsigned)s,
                               __float_as_uint(__uint_as_float(eu.y) * deg784[dl]));
    }
}

// ---------------- MFMA GEMM: C[n][128] = A'[n][128] @ W + bias ----------------
// AMODE 0: A = raw fp32 (x). AMODE 1: A = fp32 agg, fused BN+relu.
template <int AMODE>
__global__ __launch_bounds__(256) void k_gemm_mfma(const float* __restrict__ A,
                                                   const float* __restrict__ mean,
                                                   const float* __restrict__ rstd,
                                                   const __bf16* __restrict__ WT,
                                                   const float* __restrict__ bias,
                                                   __bf16* __restrict__ C, int nrows) {
    __shared__ __bf16 As[64 * PADK];
    __shared__ __bf16 Ws[128 * PADK];
    int t = threadIdx.x;
    int rowBase = blockIdx.x * 64;
    const uint4* WTg = (const uint4*)WT;
    for (int i = t; i < 2048; i += 256) {
        int n = i >> 4, k8 = i & 15;
        *(uint4*)&Ws[n * PADK + k8 * 8] = WTg[i];
    }
    const float4* A4 = (const float4*)A;
    const float4* M4 = (const float4*)mean;
    const float4* R4 = (const float4*)rstd;
    for (int i = t; i < 1024; i += 256) {
        int r = i >> 4, k8 = i & 15;
        int gr = rowBase + r;
        float4 a0 = make_float4(0.f, 0.f, 0.f, 0.f), a1 = a0;
        if (gr < nrows) {
            a0 = A4[(size_t)gr * 32 + k8 * 2];
            a1 = A4[(size_t)gr * 32 + k8 * 2 + 1];
        }
        if (AMODE == 1) {
            float4 m0 = M4[k8 * 2], m1 = M4[k8 * 2 + 1];
            float4 r0 = R4[k8 * 2], r1 = R4[k8 * 2 + 1];
            a0.x = fmaxf((a0.x - m0.x) * r0.x, 0.f); a0.y = fmaxf((a0.y - m0.y) * r0.y, 0.f);
            a0.z = fmaxf((a0.z - m0.z) * r0.z, 0.f); a0.w = fmaxf((a0.w - m0.w) * r0.w, 0.f);
            a1.x = fmaxf((a1.x - m1.x) * r1.x, 0.f); a1.y = fmaxf((a1.y - m1.y) * r1.y, 0.f);
            a1.z = fmaxf((a1.z - m1.z) * r1.z, 0.f); a1.w = fmaxf((a1.w - m1.w) * r1.w, 0.f);
        }
        bf16_8 o = { (__bf16)a0.x, (__bf16)a0.y, (__bf16)a0.z, (__bf16)a0.w,
                     (__bf16)a1.x, (__bf16)a1.y, (__bf16)a1.z, (__bf16)a1.w };
        *(bf16_8*)&As[r * PADK + k8 * 8] = o;
    }
    __syncthreads();
    int wave = t >> 6, lane = t & 63, quad = lane >> 4, m = lane & 15;
    int ar = wave * 16 + m;
    f32_4 acc[8];
#pragma unroll
    for (int i = 0; i < 8; ++i) acc[i] = (f32_4){0.f, 0.f, 0.f, 0.f};
#pragma unroll
    for (int kk = 0; kk < 4; ++kk) {
        bf16_8 a = *(const bf16_8*)&As[ar * PADK + kk * 32 + quad * 8];
#pragma unroll
        for (int n0 = 0; n0 < 8; ++n0) {
            bf16_8 b = *(const bf16_8*)&Ws[(n0 * 16 + m) * PADK + kk * 32 + quad * 8];
            acc[n0] = __builtin_amdgcn_mfma_f32_16x16x32_bf16(a, b, acc[n0], 0, 0, 0);
        }
    }
    __syncthreads();
#pragma unroll
    for (int n0 = 0; n0 < 8; ++n0) {
        int col = n0 * 16 + m;
        float bi = bias[col];
#pragma unroll
        for (int r = 0; r < 4; ++r) {
            int rr = wave * 16 + quad * 4 + r;
            As[rr * PADK + col] = (__bf16)(acc[n0][r] + bi);
        }
    }
    __syncthreads();
    uint4* Cg = (uint4*)C;
    for (int i = t; i < 1024; i += 256) {
        int r = i >> 4, k8 = i & 15;
        int gr = rowBase + r;
        if (gr < nrows) Cg[(size_t)gr * 16 + k8] = *(const uint4*)&As[r * PADK + k8 * 8];
    }
}

// ---------------- edge aggregation (compact CSR, unroll 16) + fused BN stats --------------------
__global__ __launch_bounds__(256) void k_agg(const __bf16* __restrict__ hwb,
                                             const uint2* __restrict__ esn2,
                                             const int* __restrict__ offs,
                                             const int* __restrict__ cnt,
                                             const float* __restrict__ dinv,
                                             float* __restrict__ agg,
                                             float* __restrict__ colpart) {
    __shared__ float red1[4 * 128], red2[4 * 128];
    int t = threadIdx.x;
    int n = (blockIdx.x * 256 + t) >> 6;
    int lane = t & 63, wave = t >> 6;
    float2 acc = make_float2(0.f, 0.f);
    const unsigned int* hw32 = (const unsigned int*)hwb;
    if (n < N_NODES) {
        float dvn = dinv[n];
        float2 sv = bf2f2(hw32[(size_t)n * 64 + lane]);
        acc.x = sv.x * dvn * dvn; acc.y = sv.y * dvn * dvn;   // self-loop term
        int beg = offs[n], num = cnt[n];
        for (int c0 = 0; c0 < num; c0 += 64) {                // chunked: no MAXDEG clamp
            int nn = min(64, num - c0);
            int s_l = 0; float w_l = 0.f;
            if (lane < nn) {
                uint2 e = esn2[beg + c0 + lane];
                s_l = (int)e.x;
                w_l = dinv[s_l] * __uint_as_float(e.y);       // e.y = ew*dinv[dst]
            }
            int i = 0;
            for (; i + 16 <= nn; i += 16) {
                int ss[16]; float ww[16]; unsigned uu[16];
#pragma unroll
                for (int j = 0; j < 16; ++j) { ss[j] = __shfl(s_l, i + j); ww[j] = __shfl(w_l, i + j); }
#pragma unroll
                for (int j = 0; j < 16; ++j) uu[j] = hw32[(size_t)ss[j] * 64 + lane];
#pragma unroll
                for (int j = 0; j < 16; ++j) {
                    float2 f = bf2f2(uu[j]);
                    acc.x += f.x * ww[j]; acc.y += f.y * ww[j];
                }
            }
            for (; i + 4 <= nn; i += 4) {
                int s0 = __shfl(s_l, i),     s1 = __shfl(s_l, i + 1);
                int s2 = __shfl(s_l, i + 2), s3 = __shfl(s_l, i + 3);
                float w0 = __shfl(w_l, i),     w1 = __shfl(w_l, i + 1);
                float w2 = __shfl(w_l, i + 2), w3 = __shfl(w_l, i + 3);
                unsigned u0 = hw32[(size_t)s0 * 64 + lane];
                unsigned u1 = hw32[(size_t)s1 * 64 + lane];
                unsigned u2 = hw32[(size_t)s2 * 64 + lane];
                unsigned u3 = hw32[(size_t)s3 * 64 + lane];
                float2 f0 = bf2f2(u0), f1 = bf2f2(u1), f2 = bf2f2(u2), f3 = bf2f2(u3);
                acc.x += f0.x * w0 + f1.x * w1 + f2.x * w2 + f3.x * w3;
                acc.y += f0.y * w0 + f1.y * w1 + f2.y * w2 + f3.y * w3;
            }
            for (; i < nn; ++i) {
                int s = __shfl(s_l, i);
                float w = __shfl(w_l, i);
                float2 f = bf2f2(hw32[(size_t)s * 64 + lane]);
                acc.x += f.x * w; acc.y += f.y * w;
            }
        }
        ((float2*)agg)[(size_t)n * 64 + lane] = acc;
    }
    *(float2*)&red1[wave * 128 + 2 * lane] = acc;
    *(float2*)&red2[wave * 128 + 2 * lane] = make_float2(acc.x * acc.x, acc.y * acc.y);
    __syncthreads();
    if (t < 128) {
        float s = red1[t] + red1[128 + t] + red1[256 + t] + red1[384 + t];
        float q = red2[t] + red2[128 + t] + red2[256 + t] + red2[384 + t];
        int c = blockIdx.x & (NCOPY - 1);
        unsafeAtomicAdd(&colpart[c * 128 + t], s);
        unsafeAtomicAdd(&colpart[NCOPY * 128 + c * 128 + t], q);
    }
}

// separate 1-block kernel: launch boundary = cross-XCD visibility (R7 lesson)
__global__ void k_bnfinal(float* colpart, float* mean, float* rstd) {
    int j = threadIdx.x;  // 128
    float s = 0.f, q = 0.f;
    for (int c = 0; c < NCOPY; ++c) {
        s += colpart[c * 128 + j];
        q += colpart[NCOPY * 128 + c * 128 + j];
        colpart[c * 128 + j] = 0.f;
        colpart[NCOPY * 128 + c * 128 + j] = 0.f;
    }
    float m = s * (1.0f / N_NODES);
    float v = q * (1.0f / N_NODES) - m * m;
    mean[j] = m;
    rstd[j] = rsqrtf(v + 1e-5f);
}

// ---------------- scoring prep ----------------
__global__ void k_prep(const float* __restrict__ agg, const float* __restrict__ mean,
                       const float* __restrict__ rstd, const int* __restrict__ cid,
                       const float* __restrict__ lin1w, const float* __restrict__ lin1b,
                       float* c0) {
    __shared__ float xc[128];
    int t = threadIdx.x;  // 128
    int cn = cid[0];
    float a = agg[(size_t)cn * 128 + t];
    xc[t] = fmaxf((a - mean[t]) * rstd[t], 0.f);
    __syncthreads();
    float acc = lin1b[t];
    for (int k = 0; k < 128; ++k)
        acc += xc[k] * lin1w[(size_t)(128 + k) * 128 + t];
    c0[t] = acc;
}

// ---------------- scoring: fused BN+relu staging (writes fp32 h) + MFMA + relu + dot(lin2) ------
__global__ __launch_bounds__(256) void k_score_mfma(const float* __restrict__ agg,
                                                    const float* __restrict__ mean,
                                                    const float* __restrict__ rstd,
                                                    const __bf16* __restrict__ WT,
                                                    const float* __restrict__ c0,
                                                    const float* __restrict__ svec,
                                                    const float* __restrict__ ecn,
                                                    const float* __restrict__ lin2w,
                                                    const float* __restrict__ lin2b,
                                                    float* __restrict__ scores,
                                                    float* __restrict__ hout,
                                                    int nrows) {
    __shared__ __bf16 As[64 * PADK];
    __shared__ __bf16 Ws[128 * PADK];
    __shared__ float c0s[128], svs[128], l2s[128];
    int t = threadIdx.x;
    int rowBase = blockIdx.x * 64;
    const uint4* WTg = (const uint4*)WT;
    for (int i = t; i < 2048; i += 256) {
        int n = i >> 4, k8 = i & 15;
        *(uint4*)&Ws[n * PADK + k8 * 8] = WTg[i];
    }
    const float4* A4 = (const float4*)agg;
    const float4* M4 = (const float4*)mean;
    const float4* R4 = (const float4*)rstd;
    float4* H4 = (float4*)hout;
    for (int i = t; i < 1024; i += 256) {
        int r = i >> 4, k8 = i & 15;
        int gr = rowBase + r;
        float4 a0 = make_float4(0.f, 0.f, 0.f, 0.f), a1 = a0;
        if (gr < nrows) {
            a0 = A4[(size_t)gr * 32 + k8 * 2];
            a1 = A4[(size_t)gr * 32 + k8 * 2 + 1];
        }
        float4 m0 = M4[k8 * 2], m1 = M4[k8 * 2 + 1];
        float4 r0 = R4[k8 * 2], r1 = R4[k8 * 2 + 1];
        float4 f0, f1;
        f0.x = fmaxf((a0.x - m0.x) * r0.x, 0.f); f0.y = fmaxf((a0.y - m0.y) * r0.y, 0.f);
        f0.z = fmaxf((a0.z - m0.z) * r0.z, 0.f); f0.w = fmaxf((a0.w - m0.w) * r0.w, 0.f);
        f1.x = fmaxf((a1.x - m1.x) * r1.x, 0.f); f1.y = fmaxf((a1.y - m1.y) * r1.y, 0.f);
        f1.z = fmaxf((a1.z - m1.z) * r1.z, 0.f); f1.w = fmaxf((a1.w - m1.w) * r1.w, 0.f);
        if (gr < nrows) {
            H4[(size_t)gr * 32 + k8 * 2] = f0;
            H4[(size_t)gr * 32 + k8 * 2 + 1] = f1;
        }
        bf16_8 o = { (__bf16)f0.x, (__bf16)f0.y, (__bf16)f0.z, (__bf16)f0.w,
                     (__bf16)f1.x, (__bf16)f1.y, (__bf16)f1.z, (__bf16)f1.w };
        *(bf16_8*)&As[r * PADK + k8 * 8] = o;
    }
    if (t < 128) { c0s[t] = c0[t]; svs[t] = svec[t]; l2s[t] = lin2w[t]; }
    __syncthreads();
    int wave = t >> 6, lane = t & 63, quad = lane >> 4, m = lane & 15;
    int ar = wave * 16 + m;
    f32_4 acc[8];
#pragma unroll
    for (int i = 0; i < 8; ++i) acc[i] = (f32_4){0.f, 0.f, 0.f, 0.f};
#pragma unroll
    for (int kk = 0; kk < 4; ++kk) {
        bf16_8 a = *(const bf16_8*)&As[ar * PADK + kk * 32 + quad * 8];
#pragma unroll
        for (int n0 = 0; n0 < 8; ++n0) {
            bf16_8 b = *(const bf16_8*)&Ws[(n0 * 16 + m) * PADK + kk * 32 + quad * 8];
            acc[n0] = __builtin_amdgcn_mfma_f32_16x16x32_bf16(a, b, acc[n0], 0, 0, 0);
        }
    }
    float l2b = lin2b[0];
#pragma unroll
    for (int r = 0; r < 4; ++r) {
        int row = rowBase + wave * 16 + quad * 4 + r;
        float e = (row < nrows) ? ecn[row] : 0.f;
        float partial = 0.f;
#pragma unroll
        for (int n0 = 0; n0 < 8; ++n0) {
            int col = n0 * 16 + m;
            float v = acc[n0][r] + c0s[col] + e * svs[col];
            partial += fmaxf(v, 0.f) * l2s[col];
        }
        partial += __shfl_xor(partial, 8, 16);
        partial += __shfl_xor(partial, 4, 16);
        partial += __shfl_xor(partial, 2, 16);
        partial += __shfl_xor(partial, 1, 16);
        if (m == 0 && row < nrows) scores[row] = partial + l2b;
    }
}

// ---------------- partition pooling ----------------
__global__ void k_partition(const float* __restrict__ scores, const float* __restrict__ part,
                            float* out) {
    __shared__ float red[256];
    int t = threadIdx.x;
    int p = t & 31, rg = t >> 5;
    float acc = 0.f;
    for (int r = blockIdx.x * 8 + rg; r < N_NODES; r += gridDim.x * 8)
        acc += scores[r] * part[(size_t)r * 32 + p];
    red[t] = acc;
    __syncthreads();
    if (t < 32) {
        float s = 0.f;
        for (int i = 0; i < 8; ++i) s += red[i * 32 + t];
        unsafeAtomicAdd(&out[t], s);
    }
}

// ---------------- host ----------------
extern "C" void kernel_launch(void* const* d_in, const int* in_sizes, int n_in,
                              void* d_out, int out_size, void* d_ws, size_t ws_size,
                              hipStream_t stream) {
    const float* x        = (const float*)d_in[0];
    const int*   eidx     = (const int*)d_in[1];
    const float* ew       = (const float*)d_in[2];
    const float* parts    = (const float*)d_in[3];
    const float* ecn      = (const float*)d_in[5];
    const float* conv_w   = (const float*)d_in[6];
    const float* conv_b   = (const float*)d_in[7];
    const float* lin1_w   = (const float*)d_in[8];
    const float* lin1_b   = (const float*)d_in[9];
    const float* lin2_w   = (const float*)d_in[10];
    const float* lin2_b   = (const float*)d_in[11];
    const int*   cid      = (const int*)d_in[12];

    const int* src = eidx;
    const int* dst = eidx + N_EDGES;

    char* p = (char*)d_ws;
    auto alloc = [&](size_t bytes) { char* r = p; p += (bytes + 255) & ~size_t(255); return r; };
    int*    counts  = (int*)alloc((size_t)NBKT * HB * 4);           // 200 KB
    int*    bstart  = (int*)alloc(NBKT * 4);
    uint2*  ebuf    = (uint2*)alloc((size_t)N_EDGES * 8);           // 6.4 MB bucket-sorted
    uint2*  esn2    = (uint2*)alloc((size_t)N_EDGES * 8);           // 6.4 MB compact CSR
    int*    offs    = (int*)alloc(NP * 4);
    int*    cnt     = (int*)alloc(NP * 4);
    float*  dinv    = (float*)alloc(NP * 4);
    float*  scores  = (float*)alloc(NP * 4);
    float*  colpart = (float*)alloc(2 * NCOPY * 128 * 4);
    float*  mean    = (float*)alloc(128 * 4);
    float*  rstd    = (float*)alloc(128 * 4);
    float*  c0      = (float*)alloc(128 * 4);
    float*  svec    = (float*)alloc(128 * 4);
    __bf16* WT      = (__bf16*)alloc(4 * 128 * 128 * 2);
    __bf16* hwb     = (__bf16*)alloc((size_t)N_NODES * 128 * 2);
    float*  agg     = (float*)alloc((size_t)N_NODES * 128 * 4);

    float* out_head = (float*)d_out;
    float* hbuf     = (float*)d_out + 32;

    const int GB = (N_NODES + 63) / 64;        // 782
    const int AB = (N_NODES * 64 + 255) / 256; // 12500

    k_init_wprep<<<64 + WPB + 1, 256, 0, stream>>>(colpart, out_head, conv_w, lin1_w, WT, svec);
    k_hist<<<HB, 256, 0, stream>>>(dst, counts);
    k_scan<<<1, 256, 0, stream>>>(counts, bstart);
    k_scatter<<<HB, 256, 0, stream>>>(src, dst, ew, counts, ebuf);
    k_build<<<NBKT, 256, 0, stream>>>(ebuf, bstart, esn2, offs, cnt, dinv);

    for (int l = 0; l < 3; ++l) {
        if (l == 0)
            k_gemm_mfma<0><<<GB, 256, 0, stream>>>(x, mean, rstd, WT, conv_b, hwb, N_NODES);
        else
            k_gemm_mfma<1><<<GB, 256, 0, stream>>>(agg, mean, rstd, WT + (size_t)l * 16384,
                                                   conv_b + (size_t)l * 128, hwb, N_NODES);
        k_agg<<<AB, 256, 0, stream>>>(hwb, esn2, offs, cnt, dinv, agg, colpart);
        k_bnfinal<<<1, 128, 0, stream>>>(colpart, mean, rstd);
    }

    k_prep<<<1, 128, 0, stream>>>(agg, mean, rstd, cid, lin1_w, lin1_b, c0);
    k_score_mfma<<<GB, 256, 0, stream>>>(agg, mean, rstd, WT + (size_t)3 * 16384, c0, svec,
                                         ecn, lin2_w, lin2_b, scores, hbuf, N_NODES);
    k_partition<<<256, 256, 0, stream>>>(scores, parts, out_head);
}

// Round 10
// 369.327 us; speedup vs baseline: 1.2455x; 1.2455x over previous
//
#include <hip/hip_runtime.h>

#define N_NODES 50000
#define N_EDGES 800000
#define NP 50048          // N padded
#define BKT 784           // nodes per bucket (64 buckets x 784 = 50176 >= N)
#define NBKT 64
#define BREG 16384        // fixed edge-region per bucket (mean 12500, sigma ~111 -> ~35 sigma)
#define HB 782            // scatter blocks: 782*1024 >= 800000
#define PADK 136          // 128 + 8 bf16 pad
#define NCOPY 64          // BN-stat replication
#define WPB 512           // wprep blocks

typedef __bf16 bf16_8 __attribute__((ext_vector_type(8)));
typedef float  f32_4  __attribute__((ext_vector_type(4)));

__device__ inline float2 bf2f2(unsigned int u) {
    union { unsigned int i; float f; } a, b;
    a.i = u << 16;
    b.i = u & 0xffff0000u;
    return make_float2(a.f, b.f);
}

// ---------------- init (colpart/out_head/cursor) + weight transpose + svec ----------------
__global__ void k_init_wprep(float* __restrict__ colpart, float* __restrict__ out_head,
                             int* __restrict__ cursor,
                             const float* __restrict__ conv_w, const float* __restrict__ lin1_w,
                             __bf16* __restrict__ WT, float* __restrict__ svec) {
    int b = blockIdx.x;
    if (b < 64) {
        int i = b * 256 + threadIdx.x;        // 64*256 = 16384 = 2*NCOPY*128
        colpart[i] = 0.f;
        if (i < 32) out_head[i] = 0.f;
        if (i < NBKT) cursor[i] = 0;
    } else if (b < 64 + WPB) {
        int b2 = b - 64;                      // 0..511
        int mat = b2 >> 7, n = b2 & 127, k = threadIdx.x;
        if (k < 128) {
            const float* srcm = (mat < 3) ? (conv_w + (size_t)mat * 16384) : lin1_w;
            WT[((size_t)mat * 128 + n) * 128 + k] = (__bf16)srcm[(size_t)k * 128 + n];
        }
    } else {
        int j = threadIdx.x;                  // svec = colsum of lin1_w rows 256..511
        if (j < 128) {
            float s = 0.f;
            for (int k = 256; k < 512; ++k) s += lin1_w[(size_t)k * 128 + j];
            svec[j] = s;
        }
    }
}

// ---------------- CSR build pass 1: bucket scatter w/ dynamic cursor reservation ----------------
// Per block: LDS hist of its 1024 edges -> one global atomic per (block,bucket) to reserve a
// contiguous range in the bucket's fixed region -> scatter via LDS sub-offsets. NO scan kernel.
__global__ __launch_bounds__(256) void k_scatter(const int* __restrict__ src,
                                                 const int* __restrict__ dst,
                                                 const float* __restrict__ ew,
                                                 int* __restrict__ cursor,
                                                 uint2* __restrict__ ebuf) {
    __shared__ int c[NBKT], basee[NBKT];
    int t = threadIdx.x, b = blockIdx.x;
    if (t < NBKT) c[t] = 0;
    __syncthreads();
    int e0 = b * 1024;
    int myd[4], mybkt[4];
#pragma unroll
    for (int j = 0; j < 4; ++j) {
        int e = e0 + t + j * 256;
        mybkt[j] = -1;
        if (e < N_EDGES) {
            myd[j] = dst[e];
            mybkt[j] = myd[j] / BKT;
            atomicAdd(&c[mybkt[j]], 1);
        }
    }
    __syncthreads();
    if (t < NBKT && c[t] > 0) basee[t] = atomicAdd(&cursor[t], c[t]);
    __syncthreads();
    if (t < NBKT) c[t] = 0;   // reuse as local fill
    __syncthreads();
#pragma unroll
    for (int j = 0; j < 4; ++j) {
        if (mybkt[j] >= 0) {
            int e = e0 + t + j * 256;
            int bkt = mybkt[j];
            int dl = myd[j] - bkt * BKT;                 // < 784
            int pos = basee[bkt] + atomicAdd(&c[bkt], 1);
            ebuf[(size_t)bkt * BREG + pos] =
                make_uint2(((unsigned)dl << 17) | (unsigned)src[e], __float_as_uint(ew[e]));
        }
    }
}

// ---------------- CSR build pass 2: one block per bucket -> per-node CSR + dinv -----------------
// Emits bucket-padded offs/cnt (no compaction); fuses weighted-degree/dinv; pre-mults ew*dinv[d].
__global__ __launch_bounds__(256) void k_build(const uint2* __restrict__ ebuf,
                                               const int* __restrict__ cursor,
                                               uint2* __restrict__ esn2,
                                               int* __restrict__ offs, int* __restrict__ cnt,
                                               float* __restrict__ dinv) {
    __shared__ int   c784[1024];
    __shared__ float deg784[1024];
    __shared__ int   o784[1024];
    __shared__ int   fill784[1024];
    __shared__ int   p[256];
    int b = blockIdx.x, t = threadIdx.x;
    size_t base = (size_t)b * BREG;
    int num = cursor[b];
    for (int i = t; i < 1024; i += 256) { c784[i] = 0; deg784[i] = 1.0f; fill784[i] = 0; }
    __syncthreads();
    for (int i = t; i < num; i += 256) {
        uint2 eu = ebuf[base + i];
        int dl = eu.x >> 17;
        atomicAdd(&c784[dl], 1);
        atomicAdd(&deg784[dl], __uint_as_float(eu.y));   // LDS float atomic
    }
    __syncthreads();
    for (int i = t; i < BKT; i += 256) deg784[i] = rsqrtf(deg784[i]);   // now holds dinv
    int s0 = c784[4 * t] + c784[4 * t + 1] + c784[4 * t + 2] + c784[4 * t + 3];
    p[t] = s0;
    __syncthreads();
    int own = s0;
    for (int d = 1; d < 256; d <<= 1) {
        int v = (t >= d) ? p[t - d] : 0;
        __syncthreads();
        p[t] += v;
        __syncthreads();
    }
    int e0 = p[t] - own;
    o784[4 * t] = e0;
    o784[4 * t + 1] = e0 + c784[4 * t];
    o784[4 * t + 2] = e0 + c784[4 * t] + c784[4 * t + 1];
    o784[4 * t + 3] = e0 + c784[4 * t] + c784[4 * t + 1] + c784[4 * t + 2];
    __syncthreads();
    int nb0 = b * BKT;
    for (int i = t; i < BKT; i += 256) {
        int n = nb0 + i;
        if (n < N_NODES) {
            offs[n] = (int)base + o784[i];
            cnt[n] = c784[i];
            dinv[n] = deg784[i];
        }
    }
    __syncthreads();
    for (int i = t; i < num; i += 256) {
        uint2 eu = ebuf[base + i];
        int dl = eu.x >> 17;
        int s  = (int)(eu.x & 131071u);
        int pos = (int)base + o784[dl] + atomicAdd(&fill784[dl], 1);
        esn2[pos] = make_uint2((unsigned)s,
                               __float_as_uint(__uint_as_float(eu.y) * deg784[dl]));
    }
}

// ---------------- MFMA GEMM: C[n][128] = A'[n][128] @ W + bias ----------------
// AMODE 0: A = raw fp32 (x). AMODE 1: A = fp32 agg, fused BN+relu.
template <int AMODE>
__global__ __launch_bounds__(256) void k_gemm_mfma(const float* __restrict__ A,
                                                   const float* __restrict__ mean,
                                                   const float* __restrict__ rstd,
                                                   const __bf16* __restrict__ WT,
                                                   const float* __restrict__ bias,
                                                   __bf16* __restrict__ C, int nrows) {
    __shared__ __bf16 As[64 * PADK];
    __shared__ __bf16 Ws[128 * PADK];
    int t = threadIdx.x;
    int rowBase = blockIdx.x * 64;
    const uint4* WTg = (const uint4*)WT;
    for (int i = t; i < 2048; i += 256) {
        int n = i >> 4, k8 = i & 15;
        *(uint4*)&Ws[n * PADK + k8 * 8] = WTg[i];
    }
    const float4* A4 = (const float4*)A;
    const float4* M4 = (const float4*)mean;
    const float4* R4 = (const float4*)rstd;
    for (int i = t; i < 1024; i += 256) {
        int r = i >> 4, k8 = i & 15;
        int gr = rowBase + r;
        float4 a0 = make_float4(0.f, 0.f, 0.f, 0.f), a1 = a0;
        if (gr < nrows) {
            a0 = A4[(size_t)gr * 32 + k8 * 2];
            a1 = A4[(size_t)gr * 32 + k8 * 2 + 1];
        }
        if (AMODE == 1) {
            float4 m0 = M4[k8 * 2], m1 = M4[k8 * 2 + 1];
            float4 r0 = R4[k8 * 2], r1 = R4[k8 * 2 + 1];
            a0.x = fmaxf((a0.x - m0.x) * r0.x, 0.f); a0.y = fmaxf((a0.y - m0.y) * r0.y, 0.f);
            a0.z = fmaxf((a0.z - m0.z) * r0.z, 0.f); a0.w = fmaxf((a0.w - m0.w) * r0.w, 0.f);
            a1.x = fmaxf((a1.x - m1.x) * r1.x, 0.f); a1.y = fmaxf((a1.y - m1.y) * r1.y, 0.f);
            a1.z = fmaxf((a1.z - m1.z) * r1.z, 0.f); a1.w = fmaxf((a1.w - m1.w) * r1.w, 0.f);
        }
        bf16_8 o = { (__bf16)a0.x, (__bf16)a0.y, (__bf16)a0.z, (__bf16)a0.w,
                     (__bf16)a1.x, (__bf16)a1.y, (__bf16)a1.z, (__bf16)a1.w };
        *(bf16_8*)&As[r * PADK + k8 * 8] = o;
    }
    __syncthreads();
    int wave = t >> 6, lane = t & 63, quad = lane >> 4, m = lane & 15;
    int ar = wave * 16 + m;
    f32_4 acc[8];
#pragma unroll
    for (int i = 0; i < 8; ++i) acc[i] = (f32_4){0.f, 0.f, 0.f, 0.f};
#pragma unroll
    for (int kk = 0; kk < 4; ++kk) {
        bf16_8 a = *(const bf16_8*)&As[ar * PADK + kk * 32 + quad * 8];
#pragma unroll
        for (int n0 = 0; n0 < 8; ++n0) {
            bf16_8 b = *(const bf16_8*)&Ws[(n0 * 16 + m) * PADK + kk * 32 + quad * 8];
            acc[n0] = __builtin_amdgcn_mfma_f32_16x16x32_bf16(a, b, acc[n0], 0, 0, 0);
        }
    }
    __syncthreads();
#pragma unroll
    for (int n0 = 0; n0 < 8; ++n0) {
        int col = n0 * 16 + m;
        float bi = bias[col];
#pragma unroll
        for (int r = 0; r < 4; ++r) {
            int rr = wave * 16 + quad * 4 + r;
            As[rr * PADK + col] = (__bf16)(acc[n0][r] + bi);
        }
    }
    __syncthreads();
    uint4* Cg = (uint4*)C;
    for (int i = t; i < 1024; i += 256) {
        int r = i >> 4, k8 = i & 15;
        int gr = rowBase + r;
        if (gr < nrows) Cg[(size_t)gr * 16 + k8] = *(const uint4*)&As[r * PADK + k8 * 8];
    }
}

// ---------------- edge aggregation (unroll 8, chunked) + fused BN stats -------------------------
__global__ __launch_bounds__(256) void k_agg(const __bf16* __restrict__ hwb,
                                             const uint2* __restrict__ esn2,
                                             const int* __restrict__ offs,
                                             const int* __restrict__ cnt,
                                             const float* __restrict__ dinv,
                                             float* __restrict__ agg,
                                             float* __restrict__ colpart) {
    __shared__ float red1[4 * 128], red2[4 * 128];
    int t = threadIdx.x;
    int n = (blockIdx.x * 256 + t) >> 6;
    int lane = t & 63, wave = t >> 6;
    float2 acc = make_float2(0.f, 0.f);
    const unsigned int* hw32 = (const unsigned int*)hwb;
    if (n < N_NODES) {
        float dvn = dinv[n];
        float2 sv = bf2f2(hw32[(size_t)n * 64 + lane]);
        acc.x = sv.x * dvn * dvn; acc.y = sv.y * dvn * dvn;   // self-loop term
        int beg = offs[n], num = cnt[n];
        for (int ch = 0; ch < num; ch += 64) {
            int nn = min(64, num - ch);
            int s_l = 0; float w_l = 0.f;
            if (lane < nn) {
                uint2 e = esn2[beg + ch + lane];
                s_l = (int)e.x;
                w_l = dinv[s_l] * __uint_as_float(e.y);       // e.y = ew*dinv[dst]
            }
            int i = 0;
            for (; i + 8 <= nn; i += 8) {
                int ss[8]; float ww[8]; unsigned uu[8];
#pragma unroll
                for (int j = 0; j < 8; ++j) { ss[j] = __shfl(s_l, i + j); ww[j] = __shfl(w_l, i + j); }
#pragma unroll
                for (int j = 0; j < 8; ++j) uu[j] = hw32[(size_t)ss[j] * 64 + lane];
#pragma unroll
                for (int j = 0; j < 8; ++j) {
                    float2 f = bf2f2(uu[j]);
                    acc.x += f.x * ww[j]; acc.y += f.y * ww[j];
                }
            }
            for (; i < nn; ++i) {
                int s = __shfl(s_l, i);
                float w = __shfl(w_l, i);
                float2 f = bf2f2(hw32[(size_t)s * 64 + lane]);
                acc.x += f.x * w; acc.y += f.y * w;
            }
        }
        ((float2*)agg)[(size_t)n * 64 + lane] = acc;
    }
    *(float2*)&red1[wave * 128 + 2 * lane] = acc;
    *(float2*)&red2[wave * 128 + 2 * lane] = make_float2(acc.x * acc.x, acc.y * acc.y);
    __syncthreads();
    if (t < 128) {
        float s = red1[t] + red1[128 + t] + red1[256 + t] + red1[384 + t];
        float q = red2[t] + red2[128 + t] + red2[256 + t] + red2[384 + t];
        int c = blockIdx.x & (NCOPY - 1);
        unsafeAtomicAdd(&colpart[c * 128 + t], s);
        unsafeAtomicAdd(&colpart[NCOPY * 128 + c * 128 + t], q);
    }
}

// separate 1-block kernel: launch boundary = cross-XCD visibility (R7 lesson)
__global__ void k_bnfinal(float* colpart, float* mean, float* rstd) {
    int j = threadIdx.x;  // 128
    float s = 0.f, q = 0.f;
    for (int c = 0; c < NCOPY; ++c) {
        s += colpart[c * 128 + j];
        q += colpart[NCOPY * 128 + c * 128 + j];
        colpart[c * 128 + j] = 0.f;
        colpart[NCOPY * 128 + c * 128 + j] = 0.f;
    }
    float m = s * (1.0f / N_NODES);
    float v = q * (1.0f / N_NODES) - m * m;
    mean[j] = m;
    rstd[j] = rsqrtf(v + 1e-5f);
}

// ---------------- scoring prep ----------------
__global__ void k_prep(const float* __restrict__ agg, const float* __restrict__ mean,
                       const float* __restrict__ rstd, const int* __restrict__ cid,
                       const float* __restrict__ lin1w, const float* __restrict__ lin1b,
                       float* c0) {
    __shared__ float xc[128];
    int t = threadIdx.x;  // 128
    int cn = cid[0];
    float a = agg[(size_t)cn * 128 + t];
    xc[t] = fmaxf((a - mean[t]) * rstd[t], 0.f);
    __syncthreads();
    float acc = lin1b[t];
    for (int k = 0; k < 128; ++k)
        acc += xc[k] * lin1w[(size_t)(128 + k) * 128 + t];
    c0[t] = acc;
}

// ---------------- scoring: fused BN+relu staging (writes fp32 h) + MFMA + relu + dot(lin2) ------
__global__ __launch_bounds__(256) void k_score_mfma(const float* __restrict__ agg,
                                                    const float* __restrict__ mean,
                                                    const float* __restrict__ rstd,
                                                    const __bf16* __restrict__ WT,
                                                    const float* __restrict__ c0,
                                                    const float* __restrict__ svec,
                                                    const float* __restrict__ ecn,
                                                    const float* __restrict__ lin2w,
                                                    const float* __restrict__ lin2b,
                                                    float* __restrict__ scores,
                                                    float* __restrict__ hout,
                                                    int nrows) {
    __shared__ __bf16 As[64 * PADK];
    __shared__ __bf16 Ws[128 * PADK];
    __shared__ float c0s[128], svs[128], l2s[128];
    int t = threadIdx.x;
    int rowBase = blockIdx.x * 64;
    const uint4* WTg = (const uint4*)WT;
    for (int i = t; i < 2048; i += 256) {
        int n = i >> 4, k8 = i & 15;
        *(uint4*)&Ws[n * PADK + k8 * 8] = WTg[i];
    }
    const float4* A4 = (const float4*)agg;
    const float4* M4 = (const float4*)mean;
    const float4* R4 = (const float4*)rstd;
    float4* H4 = (float4*)hout;
    for (int i = t; i < 1024; i += 256) {
        int r = i >> 4, k8 = i & 15;
        int gr = rowBase + r;
        float4 a0 = make_float4(0.f, 0.f, 0.f, 0.f), a1 = a0;
        if (gr < nrows) {
            a0 = A4[(size_t)gr * 32 + k8 * 2];
            a1 = A4[(size_t)gr * 32 + k8 * 2 + 1];
        }
        float4 m0 = M4[k8 * 2], m1 = M4[k8 * 2 + 1];
        float4 r0 = R4[k8 * 2], r1 = R4[k8 * 2 + 1];
        float4 f0, f1;
        f0.x = fmaxf((a0.x - m0.x) * r0.x, 0.f); f0.y = fmaxf((a0.y - m0.y) * r0.y, 0.f);
        f0.z = fmaxf((a0.z - m0.z) * r0.z, 0.f); f0.w = fmaxf((a0.w - m0.w) * r0.w, 0.f);
        f1.x = fmaxf((a1.x - m1.x) * r1.x, 0.f); f1.y = fmaxf((a1.y - m1.y) * r1.y, 0.f);
        f1.z = fmaxf((a1.z - m1.z) * r1.z, 0.f); f1.w = fmaxf((a1.w - m1.w) * r1.w, 0.f);
        if (gr < nrows) {
            H4[(size_t)gr * 32 + k8 * 2] = f0;
            H4[(size_t)gr * 32 + k8 * 2 + 1] = f1;
        }
        bf16_8 o = { (__bf16)f0.x, (__bf16)f0.y, (__bf16)f0.z, (__bf16)f0.w,
                     (__bf16)f1.x, (__bf16)f1.y, (__bf16)f1.z, (__bf16)f1.w };
        *(bf16_8*)&As[r * PADK + k8 * 8] = o;
    }
    if (t < 128) { c0s[t] = c0[t]; svs[t] = svec[t]; l2s[t] = lin2w[t]; }
    __syncthreads();
    int wave = t >> 6, lane = t & 63, quad = lane >> 4, m = lane & 15;
    int ar = wave * 16 + m;
    f32_4 acc[8];
#pragma unroll
    for (int i = 0; i < 8; ++i) acc[i] = (f32_4){0.f, 0.f, 0.f, 0.f};
#pragma unroll
    for (int kk = 0; kk < 4; ++kk) {
        bf16_8 a = *(const bf16_8*)&As[ar * PADK + kk * 32 + quad * 8];
#pragma unroll
        for (int n0 = 0; n0 < 8; ++n0) {
            bf16_8 b = *(const bf16_8*)&Ws[(n0 * 16 + m) * PADK + kk * 32 + quad * 8];
            acc[n0] = __builtin_amdgcn_mfma_f32_16x16x32_bf16(a, b, acc[n0], 0, 0, 0);
        }
    }
    float l2b = lin2b[0];
#pragma unroll
    for (int r = 0; r < 4; ++r) {
        int row = rowBase + wave * 16 + quad * 4 + r;
        float e = (row < nrows) ? ecn[row] : 0.f;
        float partial = 0.f;
#pragma unroll
        for (int n0 = 0; n0 < 8; ++n0) {
            int col = n0 * 16 + m;
            float v = acc[n0][r] + c0s[col] + e * svs[col];
            partial += fmaxf(v, 0.f) * l2s[col];
        }
        partial += __shfl_xor(partial, 8, 16);
        partial += __shfl_xor(partial, 4, 16);
        partial += __shfl_xor(partial, 2, 16);
        partial += __shfl_xor(partial, 1, 16);
        if (m == 0 && row < nrows) scores[row] = partial + l2b;
    }
}

// ---------------- partition pooling ----------------
__global__ void k_partition(const float* __restrict__ scores, const float* __restrict__ part,
                            float* out) {
    __shared__ float red[256];
    int t = threadIdx.x;
    int p = t & 31, rg = t >> 5;
    float acc = 0.f;
    for (int r = blockIdx.x * 8 + rg; r < N_NODES; r += gridDim.x * 8)
        acc += scores[r] * part[(size_t)r * 32 + p];
    red[t] = acc;
    __syncthreads();
    if (t < 32) {
        float s = 0.f;
        for (int i = 0; i < 8; ++i) s += red[i * 32 + t];
        unsafeAtomicAdd(&out[t], s);
    }
}

// ---------------- host ----------------
extern "C" void kernel_launch(void* const* d_in, const int* in_sizes, int n_in,
                              void* d_out, int out_size, void* d_ws, size_t ws_size,
                              hipStream_t stream) {
    const float* x        = (const float*)d_in[0];
    const int*   eidx     = (const int*)d_in[1];
    const float* ew       = (const float*)d_in[2];
    const float* parts    = (const float*)d_in[3];
    const float* ecn      = (const float*)d_in[5];
    const float* conv_w   = (const float*)d_in[6];
    const float* conv_b   = (const float*)d_in[7];
    const float* lin1_w   = (const float*)d_in[8];
    const float* lin1_b   = (const float*)d_in[9];
    const float* lin2_w   = (const float*)d_in[10];
    const float* lin2_b   = (const float*)d_in[11];
    const int*   cid      = (const int*)d_in[12];

    const int* src = eidx;
    const int* dst = eidx + N_EDGES;

    char* p = (char*)d_ws;
    auto alloc = [&](size_t bytes) { char* r = p; p += (bytes + 255) & ~size_t(255); return r; };
    int*    cursor  = (int*)alloc(NBKT * 4);
    uint2*  ebuf    = (uint2*)alloc((size_t)NBKT * BREG * 8);       // 8.4 MB bucket regions
    uint2*  esn2    = (uint2*)alloc((size_t)NBKT * BREG * 8);       // 8.4 MB node-sorted CSR
    int*    offs    = (int*)alloc(NP * 4);
    int*    cnt     = (int*)alloc(NP * 4);
    float*  dinv    = (float*)alloc(NP * 4);
    float*  scores  = (float*)alloc(NP * 4);
    float*  colpart = (float*)alloc(2 * NCOPY * 128 * 4);
    float*  mean    = (float*)alloc(128 * 4);
    float*  rstd    = (float*)alloc(128 * 4);
    float*  c0      = (float*)alloc(128 * 4);
    float*  svec    = (float*)alloc(128 * 4);
    __bf16* WT      = (__bf16*)alloc(4 * 128 * 128 * 2);
    __bf16* hwb     = (__bf16*)alloc((size_t)N_NODES * 128 * 2);
    float*  agg     = (float*)alloc((size_t)N_NODES * 128 * 4);

    float* out_head = (float*)d_out;
    float* hbuf     = (float*)d_out + 32;

    const int GB = (N_NODES + 63) / 64;        // 782
    const int AB = (N_NODES * 64 + 255) / 256; // 12500

    k_init_wprep<<<64 + WPB + 1, 256, 0, stream>>>(colpart, out_head, cursor,
                                                   conv_w, lin1_w, WT, svec);
    k_scatter<<<HB, 256, 0, stream>>>(src, dst, ew, cursor, ebuf);
    k_build<<<NBKT, 256, 0, stream>>>(ebuf, cursor, esn2, offs, cnt, dinv);

    for (int l = 0; l < 3; ++l) {
        if (l == 0)
            k_gemm_mfma<0><<<GB, 256, 0, stream>>>(x, mean, rstd, WT, conv_b, hwb, N_NODES);
        else
            k_gemm_mfma<1><<<GB, 256, 0, stream>>>(agg, mean, rstd, WT + (size_t)l * 16384,
                                                   conv_b + (size_t)l * 128, hwb, N_NODES);
        k_agg<<<AB, 256, 0, stream>>>(hwb, esn2, offs, cnt, dinv, agg, colpart);
        k_bnfinal<<<1, 128, 0, stream>>>(colpart, mean, rstd);
    }

    k_prep<<<1, 128, 0, stream>>>(agg, mean, rstd, cid, lin1_w, lin1_b, c0);
    k_score_mfma<<<GB, 256, 0, stream>>>(agg, mean, rstd, WT + (size_t)3 * 16384, c0, svec,
                                         ecn, lin2_w, lin2_b, scores, hbuf, N_NODES);
    k_partition<<<256, 256, 0, stream>>>(scores, parts, out_head);
}